// Round 6
// baseline (60.400 us; speedup 1.0000x reference)
//
#include <hip/hip_runtime.h>

#define EPSF 1e-7f

typedef float f32x2 __attribute__((ext_vector_type(2)));

// ---- DPP cross-lane helpers (VALU pipe) ----
#define DPPF0(x, ctrl) \
    __int_as_float(__builtin_amdgcn_update_dpp(0, __float_as_int(x), ctrl, 0xF, 0xF, false))

__device__ __forceinline__ float f_rcp(float x) { return __builtin_amdgcn_rcpf(x); }
__device__ __forceinline__ float wave_shr1_f(float x) { return DPPF0(x, 0x138); }

__device__ __forceinline__ float wave_max64(float x) {
    x = fmaxf(x, DPPF0(x, 0x111));   // row_shr:1
    x = fmaxf(x, DPPF0(x, 0x112));   // row_shr:2
    x = fmaxf(x, DPPF0(x, 0x114));   // row_shr:4
    x = fmaxf(x, DPPF0(x, 0x118));   // row_shr:8
    x = fmaxf(x, DPPF0(x, 0x142));   // row_bcast:15
    x = fmaxf(x, DPPF0(x, 0x143));   // row_bcast:31
    return __int_as_float(__builtin_amdgcn_readlane(__float_as_int(x), 63));
}

#define SB0() __builtin_amdgcn_sched_barrier(0)
#define WAITV(N) do { asm volatile("s_waitcnt vmcnt(" #N ")" ::: "memory"); SB0(); } while (0)

// one coalesced row load: lane l gets floats [2l, 2l+1] of row (512 B total)
#define ISS2(dst, IMM) \
    asm volatile("global_load_dwordx2 %0, %1, %2 offset:" #IMM \
                 : "=v"(dst) : "v"(voff), "s"(pn))

#define ISSUE_W8(X) do { \
    ISS2(X[0], 0);    ISS2(X[1], 512);  ISS2(X[2], 1024); ISS2(X[3], 1536); \
    ISS2(X[4], 2048); ISS2(X[5], 2560); ISS2(X[6], 3072); ISS2(X[7], 3584); \
    pn += 8 * 128; \
} while (0)

#define ISSUE_T7(X) do { \
    ISS2(X[0], 0);    ISS2(X[1], 512);  ISS2(X[2], 1024); ISS2(X[3], 1536); \
    ISS2(X[4], 2048); ISS2(X[5], 2560); ISS2(X[6], 3072); \
} while (0)

// route row values to owner lanes: ds_bpermute crossbar (conflict-free),
// blank via readlane (wave-uniform). Depends only on loaded data + static
// addresses -> fully pipelineable, independent of scan state.
#define ROUTE(X, k) \
    const int px1_##k = __builtin_amdgcn_ds_bpermute(a1, __float_as_int(X[k].x)); \
    const int py1_##k = __builtin_amdgcn_ds_bpermute(a1, __float_as_int(X[k].y)); \
    const int px3_##k = __builtin_amdgcn_ds_bpermute(a3, __float_as_int(X[k].x)); \
    const int py3_##k = __builtin_amdgcn_ds_bpermute(a3, __float_as_int(X[k].y)); \
    const float pb_##k = __int_as_float(__builtin_amdgcn_readlane(__float_as_int(X[k].y), 63)); \
    const float p1_##k = __int_as_float(sel1 ? py1_##k : px1_##k); \
    const float p3_##k = __int_as_float(sel3 ? py3_##k : px3_##k);

// ---- one CTC step (identical math to the verified round-3/4 kernels) ----
#define STEP(PB_, P1_, P3_) do { \
    const float pbe = (PB_) + EPSF; \
    const float rpb = f_rcp(pbe); \
    const float q1  = ((P1_) + EPSF) * rpb; \
    const float q3  = ((P3_) + EPSF) * rpb; \
    const float n3  = wave_shr1_f(u3); \
    const float t1  = fmaf(m1, n3, u0 + u1); \
    const float t3  = fmaf(m3, u1, u2 + u3); \
    u4 = u4 + u3; \
    u3 = t3 * q3; \
    u2 = u2 + u1; \
    u1 = t1 * q1; \
    u0 = u0 + n3; \
    O += __logf(pbe); \
} while (0)

#define APPLY() do { \
    const float rm_ = f_rcp(m_carry); \
    u0 *= rm_; u1 *= rm_; u2 *= rm_; u3 *= rm_; u4 *= rm_; \
    O += __logf(m_carry); \
} while (0)

#define SNAP() do { \
    m_carry = wave_max64(fmaxf(fmaxf(u0, u1), fmaxf(u2, fmaxf(u3, u4)))); \
} while (0)

#define STEPK(k) STEP(pb_##k, p1_##k, p3_##k)

#define CONS8(X) do { \
    ROUTE(X,0) ROUTE(X,1) ROUTE(X,2) ROUTE(X,3) \
    ROUTE(X,4) ROUTE(X,5) ROUTE(X,6) ROUTE(X,7) \
    STEPK(0); STEPK(1); APPLY(); \
    STEPK(2); STEPK(3); STEPK(4); STEPK(5); STEPK(6); STEPK(7); \
    SNAP(); \
} while (0)

#define CONS_T7(X) do { \
    ROUTE(X,0) ROUTE(X,1) ROUTE(X,2) ROUTE(X,3) \
    ROUTE(X,4) ROUTE(X,5) ROUTE(X,6) \
    STEPK(0); STEPK(1); APPLY(); \
    STEPK(2); STEPK(3); STEPK(4); STEPK(5); STEPK(6); \
} while (0)

// Specialized T=512, C=128, U=128. One wave per batch row; lane l owns states
// 4l..4l+3 (+256 on lane 63). Rows loaded coalesced (dwordx2/lane), values
// routed to owner lanes via ds_bpermute. Triple-buffered reg windows,
// counted vmcnt, zero scattered gathers, zero LDS storage.
__global__ __launch_bounds__(64, 1) void ctc_bperm512(
        const int* __restrict__ y_true, const float* __restrict__ y_pred,
        float* __restrict__ out) {
    const int b    = blockIdx.x;
    const int lane = threadIdx.x;
    const float* __restrict__ yp = y_pred + (size_t)b * (512 * 128);

    const int2 lc = ((const int2*)(y_true + (size_t)b * 128))[lane];
    const int c1 = lc.x, c3 = lc.y;
    const int cp = __builtin_amdgcn_update_dpp(0, c3, 0x138, 0xF, 0xF, false);
    const float m1 = (lane > 0 && c1 != cp) ? 1.f : 0.f;
    const float m3 = (c3 != c1) ? 1.f : 0.f;

    // bpermute routing: value p[c] lives in lane c>>1, component c&1
    const int  a1   = (c1 >> 1) << 2;
    const int  a3   = (c3 >> 1) << 2;
    const bool sel1 = (c1 & 1) != 0;
    const bool sel3 = (c3 & 1) != 0;

    float u0, u1, u2 = 0.f, u3 = 0.f, u4 = 0.f;
    {
        const float pvb = yp[127];     // blank prob at t=0
        const float pv1 = yp[c1];
        u0 = (lane == 0) ? pvb + EPSF : 0.f;
        u1 = (lane == 0) ? pv1 + EPSF : 0.f;
    }
    float O = 0.f, m_carry = 1.0f;

    const int voff = lane * 8;
    const float* pn = yp + 128;        // row 1

    WAITV(0);   // init loads retired; explicit vmcnt counting starts at 0

    f32x2 A[8], B[8], C[8];
    ISSUE_W8(A);   // W0: rows 1..8
    ISSUE_W8(B);   // W1: rows 9..16

    for (int j = 0; j < 20; ++j) {
        ISSUE_W8(C);  WAITV(16);  CONS8(A);   // consume W(3j),   issue W(3j+2)
        ISSUE_W8(A);  WAITV(16);  CONS8(B);   // consume W(3j+1), issue W(3j+3)
        ISSUE_W8(B);  WAITV(16);  CONS8(C);   // consume W(3j+2), issue W(3j+4)
    }
    // consumed W0..W59; in flight: A=W60, B=W61; pn at row 497
    ISSUE_W8(C);                    // W62: rows 497..504
    WAITV(16);  CONS8(A);           // W60 (rows 481..488)
    ISSUE_T7(A);                    // tail rows 505..511 (7 loads)
    WAITV(15);  CONS8(B);           // W61 (rows 489..496)
    WAITV(7);   CONS8(C);           // W62 (rows 497..504)
    WAITV(0);   CONS_T7(A);         // steps 505..511

    if (lane == 63) out[b] = -(O + __logf(u3 + u4));
}

// ---- generic fallback (verified round-3 kernel) for other shapes ----
__global__ __launch_bounds__(64, 1) void ctc_scan_generic(
        const int* __restrict__ y_true, const float* __restrict__ y_pred,
        float* __restrict__ out, int T, int C, int U) {
    const int b    = blockIdx.x;
    const int lane = threadIdx.x;
    const int blank = C - 1;
    const float* __restrict__ yp = y_pred + (size_t)b * T * C;

    const int2 lc = ((const int2*)(y_true + (size_t)b * U))[lane];
    const int c1 = lc.x, c3 = lc.y;
    const int cp = __builtin_amdgcn_update_dpp(0, c3, 0x138, 0xF, 0xF, false);
    const float m1 = (lane > 0 && c1 != cp) ? 1.f : 0.f;
    const float m3 = (c3 != c1) ? 1.f : 0.f;

    float u0, u1, u2 = 0.f, u3 = 0.f, u4 = 0.f;
    u0 = (lane == 0) ? yp[blank] + EPSF : 0.f;
    u1 = (lane == 0) ? yp[c1] + EPSF : 0.f;
    float O = 0.f, m_carry = 1.0f;
    int kren = 0;

    for (int t = 1; t < T; ++t) {
        const float* row = yp + (size_t)t * C;
        STEP(row[blank], row[c1], row[c3]);
        if (++kren == 8) { SNAP(); APPLY(); kren = 0; }
    }
    if (lane == 63) out[b] = -(O + __logf(u3 + u4));
}

extern "C" void kernel_launch(void* const* d_in, const int* in_sizes, int n_in,
                              void* d_out, int out_size, void* d_ws, size_t ws_size,
                              hipStream_t stream) {
    const int*   y_true = (const int*)d_in[0];
    const float* y_pred = (const float*)d_in[1];
    float*       out    = (float*)d_out;

    const int B = out_size;                 // 256
    const int U = in_sizes[0] / B;          // 128
    const int C = 128;                      // classes incl. blank
    const int T = in_sizes[1] / (B * C);    // 512

    if (T == 512 && C == 128 && U == 128) {
        ctc_bperm512<<<B, 64, 0, stream>>>(y_true, y_pred, out);
    } else {
        ctc_scan_generic<<<B, 64, 0, stream>>>(y_true, y_pred, out, T, C, U);
    }
}

// Round 8
// 41.218 us; speedup vs baseline: 1.4654x; 1.4654x over previous
//
#include <hip/hip_runtime.h>

#define EPSF 1e-7f

// ---- DPP cross-lane helpers (VALU pipe, no DS) ----
#define DPPF0(x, ctrl) \
    __int_as_float(__builtin_amdgcn_update_dpp(0, __float_as_int(x), ctrl, 0xF, 0xF, false))

__device__ __forceinline__ float f_rcp(float x) { return __builtin_amdgcn_rcpf(x); }
__device__ __forceinline__ float wave_shr1_f(float x) { return DPPF0(x, 0x138); }

__device__ __forceinline__ float wave_max64(float x) {
    x = fmaxf(x, DPPF0(x, 0x111));   // row_shr:1
    x = fmaxf(x, DPPF0(x, 0x112));   // row_shr:2
    x = fmaxf(x, DPPF0(x, 0x114));   // row_shr:4
    x = fmaxf(x, DPPF0(x, 0x118));   // row_shr:8
    x = fmaxf(x, DPPF0(x, 0x142));   // row_bcast:15
    x = fmaxf(x, DPPF0(x, 0x143));   // row_bcast:31
    return __int_as_float(__builtin_amdgcn_readlane(__float_as_int(x), 63));
}

#define SB0() __builtin_amdgcn_sched_barrier(0)
#define WAITV(N) do { asm volatile("s_waitcnt vmcnt(" #N ")" ::: "memory"); SB0(); } while (0)

// per-lane prob gather (VMEM). Wave-uniform row base in SGPR, per-lane class
// voffset, static row-within-window immediate. Verified in R4.
#define ISS(dst, voff, IMM) \
    asm volatile("global_load_dword %0, %1, %2 offset:" #IMM \
                 : "=v"(dst) : "v"(voff), "s"(pn))

// 8-row window: 24 loads (blank, c1, c3 per row)
#define GISSUE(X) do { \
    ISS(X##b[0], vb, 0);    ISS(X##1[0], v1, 0);    ISS(X##3[0], v3, 0); \
    ISS(X##b[1], vb, 512);  ISS(X##1[1], v1, 512);  ISS(X##3[1], v3, 512); \
    ISS(X##b[2], vb, 1024); ISS(X##1[2], v1, 1024); ISS(X##3[2], v3, 1024); \
    ISS(X##b[3], vb, 1536); ISS(X##1[3], v1, 1536); ISS(X##3[3], v3, 1536); \
    ISS(X##b[4], vb, 2048); ISS(X##1[4], v1, 2048); ISS(X##3[4], v3, 2048); \
    ISS(X##b[5], vb, 2560); ISS(X##1[5], v1, 2560); ISS(X##3[5], v3, 2560); \
    ISS(X##b[6], vb, 3072); ISS(X##1[6], v1, 3072); ISS(X##3[6], v3, 3072); \
    ISS(X##b[7], vb, 3584); ISS(X##1[7], v1, 3584); ISS(X##3[7], v3, 3584); \
    pn += 8 * 128; \
} while (0)

#define GISSUE_T7(X) do { \
    ISS(X##b[0], vb, 0);    ISS(X##1[0], v1, 0);    ISS(X##3[0], v3, 0); \
    ISS(X##b[1], vb, 512);  ISS(X##1[1], v1, 512);  ISS(X##3[1], v3, 512); \
    ISS(X##b[2], vb, 1024); ISS(X##1[2], v1, 1024); ISS(X##3[2], v3, 1024); \
    ISS(X##b[3], vb, 1536); ISS(X##1[3], v1, 1536); ISS(X##3[3], v3, 1536); \
    ISS(X##b[4], vb, 2048); ISS(X##1[4], v1, 2048); ISS(X##3[4], v3, 2048); \
    ISS(X##b[5], vb, 2560); ISS(X##1[5], v1, 2560); ISS(X##3[5], v3, 2560); \
    ISS(X##b[6], vb, 3072); ISS(X##1[6], v1, 3072); ISS(X##3[6], v3, 3072); \
} while (0)

// ---- one CTC step, product form: no rcp/log on the step path ----
// u_s' = (u_s + u_{s-1} + skip*u_{s-2}) * (p_s + eps)
#define PSTEP(PBE_, P1_, P3_) do { \
    const float e1 = (P1_) + EPSF; \
    const float e3 = (P3_) + EPSF; \
    const float n3 = wave_shr1_f(u3); \
    const float t1 = fmaf(m1, n3, u0 + u1); \
    const float t3 = fmaf(m3, u1, u2 + u3); \
    u4 = (u4 + u3) * (PBE_); \
    u3 = t3 * e3; \
    u2 = (u2 + u1) * (PBE_); \
    u1 = t1 * e1; \
    u0 = (u0 + n3) * (PBE_); \
} while (0)

// SNAP: wave max; rcp & log computed immediately (off the state chain)
#define SNAP(RM, LM) do { \
    float mm_ = fmaxf(fmaxf(u0, u1), fmaxf(u2, fmaxf(u3, u4))); \
    mm_ = wave_max64(mm_); \
    RM = f_rcp(mm_); \
    LM = __logf(mm_); \
} while (0)

#define APPLY(RM, LM) do { \
    u0 *= RM; u1 *= RM; u2 *= RM; u3 *= RM; u4 *= RM; \
    O += LM; \
} while (0)

#define PBE(X, k) const float pbe##k = X##b[k] + EPSF;

// 8 steps; renorm period 4, snap->apply delayed 2 steps
#define CONS8(X) do { \
    PBE(X,0) PBE(X,1) PBE(X,2) PBE(X,3) PBE(X,4) PBE(X,5) PBE(X,6) PBE(X,7) \
    PSTEP(pbe0, X##1[0], X##3[0]); \
    PSTEP(pbe1, X##1[1], X##3[1]); \
    APPLY(rmA, lmA); \
    PSTEP(pbe2, X##1[2], X##3[2]); \
    PSTEP(pbe3, X##1[3], X##3[3]); \
    SNAP(rmB, lmB); \
    PSTEP(pbe4, X##1[4], X##3[4]); \
    PSTEP(pbe5, X##1[5], X##3[5]); \
    APPLY(rmB, lmB); \
    PSTEP(pbe6, X##1[6], X##3[6]); \
    PSTEP(pbe7, X##1[7], X##3[7]); \
    SNAP(rmA, lmA); \
} while (0)

#define CONS_T7(X) do { \
    PBE(X,0) PBE(X,1) PBE(X,2) PBE(X,3) PBE(X,4) PBE(X,5) PBE(X,6) \
    PSTEP(pbe0, X##1[0], X##3[0]); \
    PSTEP(pbe1, X##1[1], X##3[1]); \
    APPLY(rmA, lmA); \
    PSTEP(pbe2, X##1[2], X##3[2]); \
    PSTEP(pbe3, X##1[3], X##3[3]); \
    SNAP(rmB, lmB); \
    PSTEP(pbe4, X##1[4], X##3[4]); \
    PSTEP(pbe5, X##1[5], X##3[5]); \
    APPLY(rmB, lmB); \
    PSTEP(pbe6, X##1[6], X##3[6]); \
} while (0)

// Specialized T=512, C=128, U=128. One wave per batch row; lane l owns states
// 4l..4l+3 (+256 on lane 63). R4-verified load skeleton (3 VMEM gathers/step,
// 3 rotating register windows, counted vmcnt; peak 48 outstanding <= 63 cap),
// product-form math: zero transcendentals on the step path.
__global__ __launch_bounds__(64, 1) void ctc_prod512(
        const int* __restrict__ y_true, const float* __restrict__ y_pred,
        float* __restrict__ out) {
    const int b    = blockIdx.x;
    const int lane = threadIdx.x;
    const float* __restrict__ yp = y_pred + (size_t)b * (512 * 128);

    const int2 lc = ((const int2*)(y_true + (size_t)b * 128))[lane];
    const int c1 = lc.x, c3 = lc.y;
    const int cp = __builtin_amdgcn_update_dpp(0, c3, 0x138, 0xF, 0xF, false);
    const float m1 = (lane > 0 && c1 != cp) ? 1.f : 0.f;
    const float m3 = (c3 != c1) ? 1.f : 0.f;

    float u0, u1, u2 = 0.f, u3 = 0.f, u4 = 0.f;
    {
        const float pvb = yp[127];     // blank prob at t=0
        const float pv1 = yp[c1];
        u0 = (lane == 0) ? pvb + EPSF : 0.f;
        u1 = (lane == 0) ? pv1 + EPSF : 0.f;
    }
    float O = 0.f;
    float rmA = 1.0f, lmA = 0.0f, rmB = 1.0f, lmB = 0.0f;

    const int vb = 127 * 4;            // blank voffset (uniform value)
    const int v1 = c1 * 4;
    const int v3 = c3 * 4;
    const float* pn = yp + 128;        // row 1 (= base of W0)

    WAITV(0);   // init loads retired; explicit vmcnt counting starts at 0

    float Ab[8], A1[8], A3[8];
    float Bb[8], B1[8], B3[8];
    float Cb[8], C1[8], C3[8];

    GISSUE(A);      // W0: rows 1..8,  pn -> row 9
    GISSUE(B);      // W1: rows 9..16, pn -> row 17

    // windows 0..59: wait (oldest window done, 24 left in flight), issue
    // W+2 (peak 48 outstanding), consume W.
    for (int j = 0; j < 20; ++j) {
        WAITV(24); GISSUE(C); CONS8(A);
        WAITV(24); GISSUE(A); CONS8(B);
        WAITV(24); GISSUE(B); CONS8(C);
    }
    // consumed W0..W59; in flight A=W60, B=W61; pn = row 497 (W62 base)
    WAITV(24); GISSUE(C);    CONS8(A);   // W60; issue W62 (rows 497..504)
    WAITV(24); GISSUE_T7(A); CONS8(B);   // W61; issue tail rows 505..511
    WAITV(21); CONS8(C);                 // W62
    WAITV(0);  CONS_T7(A);               // steps 505..511

    // loss = -(O + log(u[255] + u[256])), states live on lane 63
    if (lane == 63) out[b] = -(O + __logf(u3 + u4));
}

// ---- generic fallback for other shapes (product form, immediate renorm) ----
__global__ __launch_bounds__(64, 1) void ctc_scan_generic(
        const int* __restrict__ y_true, const float* __restrict__ y_pred,
        float* __restrict__ out, int T, int C, int U) {
    const int b    = blockIdx.x;
    const int lane = threadIdx.x;
    const int blank = C - 1;
    const float* __restrict__ yp = y_pred + (size_t)b * T * C;

    const int2 lc = ((const int2*)(y_true + (size_t)b * U))[lane];
    const int c1 = lc.x, c3 = lc.y;
    const int cp = __builtin_amdgcn_update_dpp(0, c3, 0x138, 0xF, 0xF, false);
    const float m1 = (lane > 0 && c1 != cp) ? 1.f : 0.f;
    const float m3 = (c3 != c1) ? 1.f : 0.f;

    float u0, u1, u2 = 0.f, u3 = 0.f, u4 = 0.f;
    u0 = (lane == 0) ? yp[blank] + EPSF : 0.f;
    u1 = (lane == 0) ? yp[c1] + EPSF : 0.f;
    float O = 0.f;
    float rmA = 1.0f, lmA = 0.0f;
    int kren = 0;

    for (int t = 1; t < T; ++t) {
        const float* row = yp + (size_t)t * C;
        const float pbe = row[blank] + EPSF;
        PSTEP(pbe, row[c1], row[c3]);
        if (++kren == 4) { SNAP(rmA, lmA); APPLY(rmA, lmA); kren = 0; }
    }
    if (lane == 63) out[b] = -(O + __logf(u3 + u4));
}

extern "C" void kernel_launch(void* const* d_in, const int* in_sizes, int n_in,
                              void* d_out, int out_size, void* d_ws, size_t ws_size,
                              hipStream_t stream) {
    const int*   y_true = (const int*)d_in[0];
    const float* y_pred = (const float*)d_in[1];
    float*       out    = (float*)d_out;

    const int B = out_size;                 // 256
    const int U = in_sizes[0] / B;          // 128
    const int C = 128;                      // classes incl. blank
    const int T = in_sizes[1] / (B * C);    // 512

    if (T == 512 && C == 128 && U == 128) {
        ctc_prod512<<<B, 64, 0, stream>>>(y_true, y_pred, out);
    } else {
        ctc_scan_generic<<<B, 64, 0, stream>>>(y_true, y_pred, out, T, C, U);
    }
}